// Round 11
// baseline (372.047 us; speedup 1.0000x reference)
//
#include <hip/hip_runtime.h>
#include <hip/hip_bf16.h>
#include <math.h>

namespace {
constexpr int B_ = 16, C_ = 256, L_ = 1024, NH_ = 8, DH_ = 32;

typedef __attribute__((ext_vector_type(8))) short short8v;   // 8 bf16
typedef __attribute__((ext_vector_type(4))) float float4v;   // 4 fp32

// fp32 -> bf16 RNE
__device__ __forceinline__ short f2bf(float f) {
    unsigned u = __builtin_bit_cast(unsigned, f);
    u += 0x7fffu + ((u >> 16) & 1u);
    return (short)(u >> 16);
}
__device__ __forceinline__ float bf2f(short s) {
    unsigned u = ((unsigned)(unsigned short)s) << 16;
    return __builtin_bit_cast(float, u);
}
// packed fp32x2 -> bf16x2 (v_cvt_pk_bf16_f32 on gfx950), a in low half
__device__ __forceinline__ unsigned pkrn(float a, float b) {
    float2 f; f.x = a; f.y = b;
    __hip_bfloat162 h = __float22bfloat162_rn(f);
    unsigned u;
    __builtin_memcpy(&u, &h, sizeof(u));
    return u;
}
// async global->LDS, 16B per lane; LDS dest is wave-base + lane*16 (forced)
__device__ __forceinline__ void gld16(const short* g, short* l) {
    __builtin_amdgcn_global_load_lds(
        (const __attribute__((address_space(1))) unsigned*)g,
        (__attribute__((address_space(3))) unsigned*)l, 16, 0, 0);
}

// ---------------------------------------------------------------------------
// Stack weights: WA [768][512] = [Whi|Wlo] rows {q,k,v}; WoA [256][512]
// ---------------------------------------------------------------------------
__global__ __launch_bounds__(256) void stackw_kernel(
    const float* __restrict__ wq, const float* __restrict__ wk,
    const float* __restrict__ wv, const float* __restrict__ wo,
    short* __restrict__ WA, short* __restrict__ WoA)
{
    const int g = blockIdx.x * 256 + threadIdx.x;
    if (g < 768 * 256) {
        const int o = g >> 8, cc = g & 255;
        const float* src = (o < 256) ? wq : (o < 512) ? wk : wv;
        const float v = src[(size_t)(o & 255) * 256 + cc];
        const short hi = f2bf(v);
        const short lo = f2bf(v - bf2f(hi));
        WA[(size_t)o * 512 + cc]       = hi;
        WA[(size_t)o * 512 + 256 + cc] = lo;
    } else {
        const int g2 = g - 768 * 256;
        const int o = g2 >> 8, cc = g2 & 255;
        const float v = wo[(size_t)o * 256 + cc];
        const short hi = f2bf(v);
        const short lo = f2bf(v - bf2f(hi));
        WoA[(size_t)o * 512 + cc]       = hi;
        WoA[(size_t)o * 512 + 256 + cc] = lo;
    }
}

// ---------------------------------------------------------------------------
// MFMA GEMM, BK=64, K=512 (two 256-wide W phases sharing the same X).
// EPI 0 (QKV): B staged from x fp32 [b][c][l] with fused in-LDS transpose
//   (pad-72 rows, no XOR: frag reads 2-way free). A via gld16 + XOR.
// EPI 1 (out): B = athi bf16 [b][l][c] via gld16 + XOR (original path).
// ---------------------------------------------------------------------------
template <int EPI>
__global__ __launch_bounds__(256, 3) void gemm_kernel(
    const short* __restrict__ A, const short* __restrict__ Bt, const float* __restrict__ Bx,
    const float* __restrict__ bias0, const float* __restrict__ bias1, const float* __restrict__ bias2,
    float qscale, void* __restrict__ out0, void* __restrict__ out1, void* __restrict__ out2)
{
    const int lt = blockIdx.x, ot = blockIdx.y, b = blockIdx.z;
    const int t = threadIdx.x, wv = t >> 6, lane = t & 63;
    const int quad = lane >> 4, c = lane & 15;
    const int wo = (wv & 1) * 64, wl = (wv >> 1) * 64;

    __shared__ short sA[128 * 64];   // stride-64, XOR-swizzled segments (gld16)
    __shared__ short sB[128 * 72];   // EPI0: pad-72 (VALU staging); EPI1: uses 128*64 + XOR

    float4v acc[4][4];
#pragma unroll
    for (int i = 0; i < 4; ++i)
#pragma unroll
        for (int j = 0; j < 4; ++j) acc[i][j] = (float4v)0.f;

    const short* Arow = A + (size_t)(ot * 128) * 512;
    const int srow = t >> 3, sseg = t & 7;
    const int seg = sseg ^ (srow & 7);              // source-side swizzle (gld16 paths)

    for (int kk = 0; kk < 8; ++kk) {
        __syncthreads();
        // --- stage A (weights) via async gld16, XOR segments ---
#pragma unroll
        for (int e = 0; e < 4; ++e)
            gld16(Arow + (size_t)(e * 32 + srow) * 512 + kk * 64 + seg * 8,
                  &sA[(e * 256 + t) * 8]);
        // --- stage B ---
        if constexpr (EPI == 0) {
            // fused transpose from x fp32: thread covers 4 l x 8 c
            const int cchunk = (kk & 3) * 64;
            const int ll0 = (t & 31) * 4;
            const int cs  = (t >> 5) * 8;
            float4 xv[8];
#pragma unroll
            for (int cc = 0; cc < 8; ++cc)
                xv[cc] = *(const float4*)&Bx[((size_t)b * C_ + cchunk + cs + cc) * L_ + lt * 128 + ll0];
#pragma unroll
            for (int i = 0; i < 4; ++i) {
                uint4 w;
                w.x = pkrn(((const float*)&xv[0])[i], ((const float*)&xv[1])[i]);
                w.y = pkrn(((const float*)&xv[2])[i], ((const float*)&xv[3])[i]);
                w.z = pkrn(((const float*)&xv[4])[i], ((const float*)&xv[5])[i]);
                w.w = pkrn(((const float*)&xv[6])[i], ((const float*)&xv[7])[i]);
                *(uint4*)&sB[(ll0 + i) * 72 + cs] = w;
            }
        } else {
#pragma unroll
            for (int e = 0; e < 4; ++e)
                gld16(Bt + ((size_t)b * L_ + lt * 128 + e * 32 + srow) * 256 + (kk & 3) * 64 + seg * 8,
                      &sB[(e * 256 + t) * 8]);
        }
        __syncthreads();

#pragma unroll
        for (int kc2 = 0; kc2 < 2; ++kc2) {
            short8v af[4], bf[4];
#pragma unroll
            for (int i = 0; i < 4; ++i) {
                const int row = wo + 16 * i + c;
                af[i] = *(const short8v*)&sA[row * 64 + (((kc2 * 4 + quad) ^ (c & 7)) * 8)];
            }
#pragma unroll
            for (int j = 0; j < 4; ++j) {
                const int row = wl + 16 * j + c;
                if constexpr (EPI == 0)
                    bf[j] = *(const short8v*)&sB[row * 72 + (kc2 * 4 + quad) * 8];
                else
                    bf[j] = *(const short8v*)&sB[row * 64 + (((kc2 * 4 + quad) ^ (c & 7)) * 8)];
            }
#pragma unroll
            for (int i = 0; i < 4; ++i)
#pragma unroll
                for (int j = 0; j < 4; ++j)
                    acc[i][j] = __builtin_amdgcn_mfma_f32_16x16x32_bf16(af[i], bf[j], acc[i][j], 0, 0, 0);
        }
    }

    if constexpr (EPI == 0) {
        const int typ = ot >> 1;                     // 0=q 1=k 2=v
        const int chbase = (ot & 1) * 128 + wo;
        const float* bp = (typ == 0) ? bias0 : (typ == 1) ? bias1 : bias2;
        const float sc = (typ == 0) ? qscale : 1.f;
        short* outp = (short*)((typ == 0) ? out0 : (typ == 1) ? out1 : out2);
        if (typ < 2) {
#pragma unroll
            for (int i = 0; i < 4; ++i) {
                const int ch0 = chbase + 16 * i + quad * 4;
                const int head = ch0 >> 5, d0 = ch0 & 31;
                float bias[4];
#pragma unroll
                for (int r = 0; r < 4; ++r) bias[r] = bp[ch0 + r];
#pragma unroll
                for (int j = 0; j < 4; ++j) {
                    const int l = lt * 128 + wl + 16 * j + c;
                    short4 sv;
                    sv.x = f2bf((acc[i][j][0] + bias[0]) * sc);
                    sv.y = f2bf((acc[i][j][1] + bias[1]) * sc);
                    sv.z = f2bf((acc[i][j][2] + bias[2]) * sc);
                    sv.w = f2bf((acc[i][j][3] + bias[3]) * sc);
                    *(short4*)&outp[(((size_t)b * NH_ + head) * L_ + l) * 32 + d0] = sv;
                }
            }
        } else {
#pragma unroll
            for (int i = 0; i < 4; ++i)
#pragma unroll
                for (int r = 0; r < 4; ++r) {
                    const int ch = chbase + 16 * i + quad * 4 + r;
                    const float bias = bp[ch];
#pragma unroll
                    for (int j = 0; j < 4; ++j)
                        outp[((size_t)b * C_ + ch) * L_ + lt * 128 + wl + 16 * j + c] =
                            f2bf(acc[i][j][r] + bias);
                }
        }
    } else {
        float* outp = (float*)out0;
#pragma unroll
        for (int i = 0; i < 4; ++i)
#pragma unroll
            for (int r = 0; r < 4; ++r) {
                const int ch = ot * 128 + wo + 16 * i + quad * 4 + r;
                const float bias = bias0[ch];
#pragma unroll
                for (int j = 0; j < 4; ++j)
                    outp[((size_t)b * C_ + ch) * L_ + lt * 128 + wl + 16 * j + c] =
                        acc[i][j][r] + bias;
            }
    }
}

// ---------------------------------------------------------------------------
// MFMA flash attention with 1-tile-lag PV pipeline:
//   iter i: [barrier] read kf/vf(i) from single-buffered LDS K/V into regs
//           [barrier] prefetch stage(i+1); PV(i-1) from pT[(i-1)&1] + vfp;
//           S(i) -> exp2 -> write pT[i&1]; vfp = vf.
// P^T LDS round-trip leaves the critical path (read targets ~500-cyc-old
// writes). sPT un-padded with 16B-granule XOR swizzle G^(c&7) (2-way, free);
// granule G holds keys 8G..8G+7 on both sides. LDS = 8K KV + 32K pT = 40 KB
// -> exactly 4 blocks/CU.
// ---------------------------------------------------------------------------
__global__ __launch_bounds__(256, 4) void attn_kernel(
    const short* __restrict__ qt,   // [b][h][l][d] bf16 (scale*log2e folded)
    const short* __restrict__ kt,   // [b][h][l][d] bf16
    const short* __restrict__ vb,   // [b][c][l]    bf16
    short* __restrict__ athi)       // [b][l][c]    bf16
{
    const int flat = blockIdx.x;
    const int g = ((flat >> 6) << 3) | (flat & 7);  // (b,h) group -> one XCD
    const int chunk = (flat >> 3) & 7;
    const int b = g >> 3, h = g & 7;
    const int t = threadIdx.x;
    const int wv = t >> 6, lane = t & 63;
    const int quad = lane >> 4, c = lane & 15;
    const int lq0 = chunk * 128 + wv * 32;          // wave's 32 queries

    __shared__ __align__(16) short sK[64 * 32];         // single-buffered
    __shared__ __align__(16) short sV[2][32 * 32];
    __shared__ __align__(16) short sPT[2][4][2][16][64];  // [lag][wave][qf][c][key]

    const size_t bh = (size_t)b * NH_ + h;
    const short* qbase = qt + (bh * L_) * 32;
    const short* kbase = kt + (bh * L_) * 32;
    const size_t vrow = (size_t)b * C_ + h * DH_;

    short8v qfrag[2];
#pragma unroll
    for (int qf = 0; qf < 2; ++qf)
        qfrag[qf] = *(const short8v*)(qbase + (size_t)(lq0 + qf * 16 + c) * 32 + quad * 8);

    float lp4[2][4];
#pragma unroll
    for (int qf = 0; qf < 2; ++qf)
#pragma unroll
        for (int r = 0; r < 4; ++r) lp4[qf][r] = 0.f;
    float4v o_acc[2][2];
#pragma unroll
    for (int qf = 0; qf < 2; ++qf) { o_acc[qf][0] = (float4v)0.f; o_acc[qf][1] = (float4v)0.f; }

    auto stage = [&](int m0) {
        gld16(kbase + (size_t)(m0 + (t >> 2)) * 32 + (t & 3) * 8, &sK[t * 8]);
        gld16(vb + (vrow + ((t >> 2) & 31)) * L_ + m0 + (t >> 7) * 32 + (t & 3) * 8,
              (short*)sV + t * 8);
    };

    stage(0);

    short8v vf[2][2], vfp[2][2];

#pragma unroll
    for (int i = 0; i <= 16; ++i) {
        short8v kf[4];
        if (i < 16) {
            __syncthreads();                 // stage(i) visible (vmcnt drained)
#pragma unroll
            for (int kb = 0; kb < 4; ++kb)
                kf[kb] = *(const short8v*)&sK[(kb * 16 + c) * 32 + quad * 8];
#pragma unroll
            for (int kc = 0; kc < 2; ++kc)
#pragma unroll
                for (int nb2 = 0; nb2 < 2; ++nb2)
                    vf[kc][nb2] = *(const short8v*)&sV[kc][(nb2 * 16 + c) * 32 + quad * 8];
            __syncthreads();                 // reg reads done; K/V buffers free
            if (i < 15) stage((i + 1) * 64);
        }

        // PV for tile i-1 (lagged; pT writes are a full tile old)
        if (i > 0) {
            const int pb = (i - 1) & 1;
#pragma unroll
            for (int qf = 0; qf < 2; ++qf)
#pragma unroll
                for (int kc = 0; kc < 2; ++kc) {
                    const int G = (kc * 4 + quad) ^ (c & 7);
                    const short8v pf = *(const short8v*)&sPT[pb][wv][qf][c][G * 8];
#pragma unroll
                    for (int nb2 = 0; nb2 < 2; ++nb2)
                        o_acc[qf][nb2] = __builtin_amdgcn_mfma_f32_16x16x32_bf16(vfp[kc][nb2], pf, o_acc[qf][nb2], 0, 0, 0);
                }
        }

        // S/exp/pack/write for tile i
        if (i < 16) {
            float4v st[2][4];
#pragma unroll
            for (int qf = 0; qf < 2; ++qf)
#pragma unroll
                for (int kb = 0; kb < 4; ++kb)
                    st[qf][kb] = __builtin_amdgcn_mfma_f32_16x16x32_bf16(kf[kb], qfrag[qf], (float4v)0.f, 0, 0, 0);
#pragma unroll
            for (int qf = 0; qf < 2; ++qf)
#pragma unroll
                for (int kb = 0; kb < 4; ++kb) {
                    float p[4];
#pragma unroll
                    for (int r = 0; r < 4; ++r) {
                        p[r] = __builtin_amdgcn_exp2f(st[qf][kb][r]);
                        lp4[qf][r] += p[r];
                    }
                    uint2 w;
                    w.x = pkrn(p[0], p[1]);
                    w.y = pkrn(p[2], p[3]);
                    const int Gw = (kb * 2 + (quad >> 1)) ^ (c & 7);
                    *(uint2*)&sPT[i & 1][wv][qf][c][Gw * 8 + (quad & 1) * 4] = w;
                }
#pragma unroll
            for (int kc = 0; kc < 2; ++kc)
#pragma unroll
                for (int nb2 = 0; nb2 < 2; ++nb2) vfp[kc][nb2] = vf[kc][nb2];
        }
    }

#pragma unroll
    for (int qf = 0; qf < 2; ++qf) {
        float l = (lp4[qf][0] + lp4[qf][1]) + (lp4[qf][2] + lp4[qf][3]);
        l += __shfl_xor(l, 16);
        l += __shfl_xor(l, 32);
        const float inv = 1.f / l;
#pragma unroll
        for (int nb2 = 0; nb2 < 2; ++nb2) {
            short4 sv;
            sv.x = f2bf(o_acc[qf][nb2][0] * inv);
            sv.y = f2bf(o_acc[qf][nb2][1] * inv);
            sv.z = f2bf(o_acc[qf][nb2][2] * inv);
            sv.w = f2bf(o_acc[qf][nb2][3] * inv);
            *(short4*)&athi[((size_t)b * L_ + lq0 + qf * 16 + c) * C_ + h * DH_ + nb2 * 16 + quad * 4] = sv;
        }
    }
}

}  // namespace

extern "C" void kernel_launch(void* const* d_in, const int* in_sizes, int n_in,
                              void* d_out, int out_size, void* d_ws, size_t ws_size,
                              hipStream_t stream) {
    const float* x   = (const float*)d_in[0];
    const float* w_q = (const float*)d_in[1];
    const float* b_q = (const float*)d_in[2];
    const float* w_k = (const float*)d_in[3];
    const float* b_k = (const float*)d_in[4];
    const float* w_v = (const float*)d_in[5];
    const float* b_v = (const float*)d_in[6];
    const float* w_o = (const float*)d_in[7];
    const float* b_o = (const float*)d_in[8];
    float* out = (float*)d_out;

    const size_t NT = (size_t)B_ * L_ * C_;   // 4,194,304
    short* WA   = (short*)d_ws;               // 768*512
    short* WoA  = WA + 768 * 512;             // 256*512
    short* qt   = WoA + 256 * 512;
    short* kt   = qt + NT;
    short* vb   = kt + NT;
    short* athi = vb + NT;

    const float scale_q = 0.17677669529663687f * 1.4426950408889634f; // 1/sqrt(32)*log2(e)

    stackw_kernel<<<dim3(1024), 256, 0, stream>>>(w_q, w_k, w_v, w_o, WA, WoA);
    gemm_kernel<0><<<dim3(L_ / 128, 6, B_), 256, 0, stream>>>(
        WA, nullptr, x, b_q, b_k, b_v, scale_q, qt, kt, vb);
    attn_kernel<<<dim3(1024), 256, 0, stream>>>(qt, kt, vb, athi);
    gemm_kernel<1><<<dim3(L_ / 128, 2, B_), 256, 0, stream>>>(
        WoA, athi, nullptr, b_o, nullptr, nullptr, 1.f, out, nullptr, nullptr);
}

// Round 12
// 148.498 us; speedup vs baseline: 2.5054x; 2.5054x over previous
//
#include <hip/hip_runtime.h>
#include <hip/hip_bf16.h>
#include <math.h>

namespace {
constexpr int B_ = 16, C_ = 256, L_ = 1024, NH_ = 8, DH_ = 32;

typedef __attribute__((ext_vector_type(8))) short short8v;   // 8 bf16
typedef __attribute__((ext_vector_type(4))) float float4v;   // 4 fp32

// fp32 -> bf16 RNE
__device__ __forceinline__ short f2bf(float f) {
    unsigned u = __builtin_bit_cast(unsigned, f);
    u += 0x7fffu + ((u >> 16) & 1u);
    return (short)(u >> 16);
}
__device__ __forceinline__ float bf2f(short s) {
    unsigned u = ((unsigned)(unsigned short)s) << 16;
    return __builtin_bit_cast(float, u);
}
// packed fp32x2 -> bf16x2 (v_cvt_pk_bf16_f32 on gfx950), a in low half
__device__ __forceinline__ unsigned pkrn(float a, float b) {
    float2 f; f.x = a; f.y = b;
    __hip_bfloat162 h = __float22bfloat162_rn(f);
    unsigned u;
    __builtin_memcpy(&u, &h, sizeof(u));
    return u;
}
// async global->LDS, 16B per lane; LDS dest is wave-base + lane*16 (forced)
__device__ __forceinline__ void gld16(const short* g, short* l) {
    __builtin_amdgcn_global_load_lds(
        (const __attribute__((address_space(1))) unsigned*)g,
        (__attribute__((address_space(3))) unsigned*)l, 16, 0, 0);
}

// ---------------------------------------------------------------------------
// x [b][c][l] fp32  ->  Xt hi bf16 [b][l][c]   (64x64 LDS transpose tiles)
// ---------------------------------------------------------------------------
__global__ __launch_bounds__(256) void xpose_kernel(
    const float* __restrict__ x, short* __restrict__ xthi)
{
    const int lt = blockIdx.x, ct = blockIdx.y, b = blockIdx.z;
    const int t = threadIdx.x;
    __shared__ float sX[64][68];

#pragma unroll
    for (int e = 0; e < 4; ++e) {
        const int row = e * 16 + (t >> 4);          // local c
        const int col = (t & 15) * 4;               // local l
        float4 v = *(const float4*)&x[((size_t)b * C_ + ct * 64 + row) * L_ + lt * 64 + col];
        *(float4*)&sX[row][col] = v;
    }
    __syncthreads();

    const int l = t & 63, cg = t >> 6;              // 16 channels per thread
    short hi[16];
#pragma unroll
    for (int i = 0; i < 16; ++i) hi[i] = f2bf(sX[cg * 16 + i][l]);
    const size_t base = ((size_t)b * L_ + lt * 64 + l) * C_ + ct * 64 + cg * 16;
    *(short8v*)&xthi[base]     = *(short8v*)&hi[0];
    *(short8v*)&xthi[base + 8] = *(short8v*)&hi[8];
}

// ---------------------------------------------------------------------------
// Stack weights: WA [768][512] = [Whi|Wlo] rows {q,k,v}; WoA [256][512]
// ---------------------------------------------------------------------------
__global__ __launch_bounds__(256) void stackw_kernel(
    const float* __restrict__ wq, const float* __restrict__ wk,
    const float* __restrict__ wv, const float* __restrict__ wo,
    short* __restrict__ WA, short* __restrict__ WoA)
{
    const int g = blockIdx.x * 256 + threadIdx.x;
    if (g < 768 * 256) {
        const int o = g >> 8, cc = g & 255;
        const float* src = (o < 256) ? wq : (o < 512) ? wk : wv;
        const float v = src[(size_t)(o & 255) * 256 + cc];
        const short hi = f2bf(v);
        const short lo = f2bf(v - bf2f(hi));
        WA[(size_t)o * 512 + cc]       = hi;
        WA[(size_t)o * 512 + 256 + cc] = lo;
    } else {
        const int g2 = g - 768 * 256;
        const int o = g2 >> 8, cc = g2 & 255;
        const float v = wo[(size_t)o * 256 + cc];
        const short hi = f2bf(v);
        const short lo = f2bf(v - bf2f(hi));
        WoA[(size_t)o * 512 + cc]       = hi;
        WoA[(size_t)o * 512 + 256 + cc] = lo;
    }
}

// ---------------------------------------------------------------------------
// MFMA GEMM, BK=64 (8 barriers, 32 MFMA/barrier), XOR-swizzled staging.
// ---------------------------------------------------------------------------
template <int KTOT, int EPI>
__global__ __launch_bounds__(256, 3) void gemm_kernel(
    const short* __restrict__ A, const short* __restrict__ B0,
    const float* __restrict__ bias0, const float* __restrict__ bias1, const float* __restrict__ bias2,
    float qscale, void* __restrict__ out0, void* __restrict__ out1, void* __restrict__ out2)
{
    const int lt = blockIdx.x, ot = blockIdx.y, b = blockIdx.z;
    const int t = threadIdx.x, wv = t >> 6, lane = t & 63;
    const int quad = lane >> 4, c = lane & 15;
    const int wo = (wv & 1) * 64, wl = (wv >> 1) * 64;

    __shared__ short sA[128 * 64];   // [row][k64], swizzled segments
    __shared__ short sB[128 * 64];

    float4v acc[4][4];
#pragma unroll
    for (int i = 0; i < 4; ++i)
#pragma unroll
        for (int j = 0; j < 4; ++j) acc[i][j] = (float4v)0.f;

    const short* Arow = A + (size_t)(ot * 128) * KTOT;
    const int srow = t >> 3, sseg = t & 7;
    const int seg = sseg ^ (srow & 7);              // source-side swizzle

    for (int kk = 0; kk < KTOT / 64; ++kk) {
        __syncthreads();
#pragma unroll
        for (int e = 0; e < 4; ++e) {
            gld16(Arow + (size_t)(e * 32 + srow) * KTOT + kk * 64 + seg * 8,
                  &sA[(e * 256 + t) * 8]);
            gld16(B0 + ((size_t)b * L_ + lt * 128 + e * 32 + srow) * 256 + (kk & 3) * 64 + seg * 8,
                  &sB[(e * 256 + t) * 8]);
        }
        __syncthreads();

#pragma unroll
        for (int kc2 = 0; kc2 < 2; ++kc2) {
            short8v af[4], bf[4];
#pragma unroll
            for (int i = 0; i < 4; ++i) {
                const int row = wo + 16 * i + c;
                af[i] = *(const short8v*)&sA[row * 64 + (((kc2 * 4 + quad) ^ (c & 7)) * 8)];
            }
#pragma unroll
            for (int j = 0; j < 4; ++j) {
                const int row = wl + 16 * j + c;
                bf[j] = *(const short8v*)&sB[row * 64 + (((kc2 * 4 + quad) ^ (c & 7)) * 8)];
            }
#pragma unroll
            for (int i = 0; i < 4; ++i)
#pragma unroll
                for (int j = 0; j < 4; ++j)
                    acc[i][j] = __builtin_amdgcn_mfma_f32_16x16x32_bf16(af[i], bf[j], acc[i][j], 0, 0, 0);
        }
    }

    if constexpr (EPI == 0) {
        const int typ = ot >> 1;                     // 0=q 1=k 2=v
        const int chbase = (ot & 1) * 128 + wo;
        const float* bp = (typ == 0) ? bias0 : (typ == 1) ? bias1 : bias2;
        const float sc = (typ == 0) ? qscale : 1.f;
        short* outp = (short*)((typ == 0) ? out0 : (typ == 1) ? out1 : out2);
        if (typ < 2) {
#pragma unroll
            for (int i = 0; i < 4; ++i) {
                const int ch0 = chbase + 16 * i + quad * 4;
                const int head = ch0 >> 5, d0 = ch0 & 31;
                float bias[4];
#pragma unroll
                for (int r = 0; r < 4; ++r) bias[r] = bp[ch0 + r];
#pragma unroll
                for (int j = 0; j < 4; ++j) {
                    const int l = lt * 128 + wl + 16 * j + c;
                    short4 sv;
                    sv.x = f2bf((acc[i][j][0] + bias[0]) * sc);
                    sv.y = f2bf((acc[i][j][1] + bias[1]) * sc);
                    sv.z = f2bf((acc[i][j][2] + bias[2]) * sc);
                    sv.w = f2bf((acc[i][j][3] + bias[3]) * sc);
                    *(short4*)&outp[(((size_t)b * NH_ + head) * L_ + l) * 32 + d0] = sv;
                }
            }
        } else {
#pragma unroll
            for (int i = 0; i < 4; ++i)
#pragma unroll
                for (int r = 0; r < 4; ++r) {
                    const int ch = chbase + 16 * i + quad * 4 + r;
                    const float bias = bp[ch];
#pragma unroll
                    for (int j = 0; j < 4; ++j)
                        outp[((size_t)b * C_ + ch) * L_ + lt * 128 + wl + 16 * j + c] =
                            f2bf(acc[i][j][r] + bias);
                }
        }
    } else {
        float* outp = (float*)out0;
#pragma unroll
        for (int i = 0; i < 4; ++i)
#pragma unroll
            for (int r = 0; r < 4; ++r) {
                const int ch = ot * 128 + wo + 16 * i + quad * 4 + r;
                const float bias = bias0[ch];
#pragma unroll
                for (int j = 0; j < 4; ++j)
                    outp[((size_t)b * C_ + ch) * L_ + lt * 128 + wl + 16 * j + c] =
                        acc[i][j][r] + bias;
            }
    }
}

// ---------------------------------------------------------------------------
// MFMA flash attention, 1-tile-lag PV pipeline, ROLLED loop (no unroll:
// R11's full unroll caused scratch spill, WRITE_SIZE 457 MB).
//   per tile i: [barrier] kf/vf(i) LDS->regs; [barrier] stage(i+1);
//   PV(i-1) from pT[(i-1)&1] (writes a full tile old; loop-top barrier
//   already drained lgkm -> no wait) + vfp regs; S(i)->exp2->write pT[i&1].
// sPT un-padded, 16B-granule XOR swizzle (2-way = free). LDS = 4K K + 4K V
// + 32K pT = 40 KB -> exactly 4 blocks/CU.
// ---------------------------------------------------------------------------
__global__ __launch_bounds__(256, 4) void attn_kernel(
    const short* __restrict__ qt,   // [b][h][l][d] bf16 (scale*log2e folded)
    const short* __restrict__ kt,   // [b][h][l][d] bf16
    const short* __restrict__ vb,   // [b][c][l]    bf16
    short* __restrict__ athi)       // [b][l][c]    bf16
{
    const int flat = blockIdx.x;
    const int g = ((flat >> 6) << 3) | (flat & 7);  // (b,h) group -> one XCD
    const int chunk = (flat >> 3) & 7;
    const int b = g >> 3, h = g & 7;
    const int t = threadIdx.x;
    const int wv = t >> 6, lane = t & 63;
    const int quad = lane >> 4, c = lane & 15;
    const int lq0 = chunk * 128 + wv * 32;          // wave's 32 queries

    __shared__ __align__(16) short sK[64 * 32];           // single-buffered
    __shared__ __align__(16) short sV[2][32 * 32];
    __shared__ __align__(16) short sPT[2][4][2][16][64];  // [lag][wave][qf][c][key]

    const size_t bh = (size_t)b * NH_ + h;
    const short* qbase = qt + (bh * L_) * 32;
    const short* kbase = kt + (bh * L_) * 32;
    const size_t vrow = (size_t)b * C_ + h * DH_;

    short8v qfrag[2];
#pragma unroll
    for (int qf = 0; qf < 2; ++qf)
        qfrag[qf] = *(const short8v*)(qbase + (size_t)(lq0 + qf * 16 + c) * 32 + quad * 8);

    float lp4[2][4];
#pragma unroll
    for (int qf = 0; qf < 2; ++qf)
#pragma unroll
        for (int r = 0; r < 4; ++r) lp4[qf][r] = 0.f;
    float4v o_acc[2][2];
#pragma unroll
    for (int qf = 0; qf < 2; ++qf) { o_acc[qf][0] = (float4v)0.f; o_acc[qf][1] = (float4v)0.f; }

    auto stage = [&](int m0) {
        gld16(kbase + (size_t)(m0 + (t >> 2)) * 32 + (t & 3) * 8, &sK[t * 8]);
        gld16(vb + (vrow + ((t >> 2) & 31)) * L_ + m0 + (t >> 7) * 32 + (t & 3) * 8,
              (short*)sV + t * 8);
    };

    stage(0);

    short8v vfp[2][2];

    for (int i = 0; i <= 16; ++i) {                // ROLLED — do not unroll
        short8v kf[4], vf[2][2];
        if (i < 16) {
            __syncthreads();                 // stage(i) visible (vmcnt+lgkm drained)
#pragma unroll
            for (int kb = 0; kb < 4; ++kb)
                kf[kb] = *(const short8v*)&sK[(kb * 16 + c) * 32 + quad * 8];
#pragma unroll
            for (int kc = 0; kc < 2; ++kc)
#pragma unroll
                for (int nb2 = 0; nb2 < 2; ++nb2)
                    vf[kc][nb2] = *(const short8v*)&sV[kc][(nb2 * 16 + c) * 32 + quad * 8];
            __syncthreads();                 // reg reads done; K/V buffers free
            if (i < 15) stage((i + 1) * 64);
        }

        // PV for tile i-1: pf reads hit writes from the previous iteration
        // (already drained by the loop-top barrier -> no lgkm stall)
        if (i > 0) {
            const int pb = (i - 1) & 1;
#pragma unroll
            for (int qf = 0; qf < 2; ++qf)
#pragma unroll
                for (int kc = 0; kc < 2; ++kc) {
                    const int G = (kc * 4 + quad) ^ (c & 7);
                    const short8v pf = *(const short8v*)&sPT[pb][wv][qf][c][G * 8];
#pragma unroll
                    for (int nb2 = 0; nb2 < 2; ++nb2)
                        o_acc[qf][nb2] = __builtin_amdgcn_mfma_f32_16x16x32_bf16(vfp[kc][nb2], pf, o_acc[qf][nb2], 0, 0, 0);
                }
        }

        // S/exp/pack/write for tile i
        if (i < 16) {
            const int cb = i & 1;
            float4v st[2][4];
#pragma unroll
            for (int qf = 0; qf < 2; ++qf)
#pragma unroll
                for (int kb = 0; kb < 4; ++kb)
                    st[qf][kb] = __builtin_amdgcn_mfma_f32_16x16x32_bf16(kf[kb], qfrag[qf], (float4v)0.f, 0, 0, 0);
#pragma unroll
            for (int qf = 0; qf < 2; ++qf)
#pragma unroll
                for (int kb = 0; kb < 4; ++kb) {
                    float p[4];
#pragma unroll
                    for (int r = 0; r < 4; ++r) {
                        p[r] = __builtin_amdgcn_exp2f(st[qf][kb][r]);
                        lp4[qf][r] += p[r];
                    }
                    uint2 w;
                    w.x = pkrn(p[0], p[1]);
                    w.y = pkrn(p[2], p[3]);
                    const int Gw = (kb * 2 + (quad >> 1)) ^ (c & 7);
                    *(uint2*)&sPT[cb][wv][qf][c][Gw * 8 + (quad & 1) * 4] = w;
                }
#pragma unroll
            for (int kc = 0; kc < 2; ++kc)
#pragma unroll
                for (int nb2 = 0; nb2 < 2; ++nb2) vfp[kc][nb2] = vf[kc][nb2];
        }
    }

#pragma unroll
    for (int qf = 0; qf < 2; ++qf) {
        float l = (lp4[qf][0] + lp4[qf][1]) + (lp4[qf][2] + lp4[qf][3]);
        l += __shfl_xor(l, 16);
        l += __shfl_xor(l, 32);
        const float inv = 1.f / l;
#pragma unroll
        for (int nb2 = 0; nb2 < 2; ++nb2) {
            short4 sv;
            sv.x = f2bf(o_acc[qf][nb2][0] * inv);
            sv.y = f2bf(o_acc[qf][nb2][1] * inv);
            sv.z = f2bf(o_acc[qf][nb2][2] * inv);
            sv.w = f2bf(o_acc[qf][nb2][3] * inv);
            *(short4*)&athi[((size_t)b * L_ + lq0 + qf * 16 + c) * C_ + h * DH_ + nb2 * 16 + quad * 4] = sv;
        }
    }
}

}  // namespace

extern "C" void kernel_launch(void* const* d_in, const int* in_sizes, int n_in,
                              void* d_out, int out_size, void* d_ws, size_t ws_size,
                              hipStream_t stream) {
    const float* x   = (const float*)d_in[0];
    const float* w_q = (const float*)d_in[1];
    const float* b_q = (const float*)d_in[2];
    const float* w_k = (const float*)d_in[3];
    const float* b_k = (const float*)d_in[4];
    const float* w_v = (const float*)d_in[5];
    const float* b_v = (const float*)d_in[6];
    const float* w_o = (const float*)d_in[7];
    const float* b_o = (const float*)d_in[8];
    float* out = (float*)d_out;

    const size_t NT = (size_t)B_ * L_ * C_;   // 4,194,304
    short* xthi = (short*)d_ws;
    short* WA   = xthi + NT;                  // 768*512
    short* WoA  = WA + 768 * 512;             // 256*512
    short* qt   = WoA + 256 * 512;
    short* kt   = qt + NT;
    short* vb   = kt + NT;
    short* athi = vb + NT;

    const float scale_q = 0.17677669529663687f * 1.4426950408889634f; // 1/sqrt(32)*log2(e)

    xpose_kernel<<<dim3(L_ / 64, C_ / 64, B_), 256, 0, stream>>>(x, xthi);
    stackw_kernel<<<dim3(1024), 256, 0, stream>>>(w_q, w_k, w_v, w_o, WA, WoA);
    gemm_kernel<512, 0><<<dim3(L_ / 128, 6, B_), 256, 0, stream>>>(
        WA, xthi, b_q, b_k, b_v, scale_q, qt, kt, vb);
    attn_kernel<<<dim3(1024), 256, 0, stream>>>(qt, kt, vb, athi);
    gemm_kernel<512, 1><<<dim3(L_ / 128, 2, B_), 256, 0, stream>>>(
        WoA, athi, b_o, nullptr, nullptr, 1.f, out, nullptr, nullptr);
}